// Round 1
// baseline (338.379 us; speedup 1.0000x reference)
//
#include <hip/hip_runtime.h>
#include <hip/hip_bf16.h>

// Problem: B=4096, D=1024, H=1024. Single LSTM cell step.
// gates[B][4H] = [x|h] @ [w_ih|w_hh]^T + (b_ih+b_hh); then pointwise.
#define TB 4096
#define TD 1024
#define TH 1024
#define TK 2048   // D + H
#define KSTEPS 64 // TK / 32

typedef __bf16 bf16;
typedef __bf16 bf16x8 __attribute__((ext_vector_type(8)));
typedef float f32x4 __attribute__((ext_vector_type(4)));
typedef unsigned short us4_t __attribute__((ext_vector_type(4)));

__device__ __forceinline__ void gload16(const void* g, void* l) {
  __builtin_amdgcn_global_load_lds(
      (const __attribute__((address_space(1))) void*)g,
      (__attribute__((address_space(3))) void*)l, 16, 0, 0);
}

// fp32 -> (hi, lo) bf16 split for U=[x|h] (4096x2048) and W=[w_ih|w_hh] (4096x2048)
__global__ void __launch_bounds__(256) k_convert(
    const float* __restrict__ x, const float* __restrict__ h0,
    const float* __restrict__ w_ih, const float* __restrict__ w_hh,
    bf16* __restrict__ Uhi, bf16* __restrict__ Ulo,
    bf16* __restrict__ Whi, bf16* __restrict__ Wlo) {
  int t = blockIdx.x * 256 + threadIdx.x;
  const int perMat = (TB * TK) / 4;  // threads per matrix (4 elems/thread)
  const bool isW = t >= perMat;
  int tt = isW ? t - perMat : t;
  long e0 = (long)tt * 4;
  int row = (int)(e0 >> 11);       // 2048 per row
  int k = (int)(e0 & (TK - 1));
  const float* src;
  if (!isW)
    src = (k < TD) ? (x + (size_t)row * TD + k) : (h0 + (size_t)row * TH + (k - TD));
  else
    src = (k < TD) ? (w_ih + (size_t)row * TD + k) : (w_hh + (size_t)row * TH + (k - TD));
  float4 v = *(const float4*)src;
  float vv[4] = {v.x, v.y, v.z, v.w};
  us4_t hv, lv;
#pragma unroll
  for (int i = 0; i < 4; ++i) {
    bf16 hb = (bf16)vv[i];
    float rem = vv[i] - (float)hb;
    bf16 lb = (bf16)rem;
    hv[i] = __builtin_bit_cast(unsigned short, hb);
    lv[i] = __builtin_bit_cast(unsigned short, lb);
  }
  size_t off = (size_t)row * TK + k;
  bf16* dh = (isW ? Whi : Uhi) + off;
  bf16* dl = (isW ? Wlo : Ulo) + off;
  *(us4_t*)dh = hv;
  *(us4_t*)dl = lv;
}

// Fused split-bf16 GEMM + LSTM pointwise.
// Block tile: 128 U-rows x 32 h-cols; the 128 N-cols of the GEMM tile are the
// 4 gate strips (q*1024 + hcBase + 0..31). Wave w owns rows [w*32, w*32+32),
// all 128 N-cols -> each lane holds matching i/f/g/o in acc frags n0, n0+2,
// n0+4, n0+6 (same lane, same reg) -> fully in-register epilogue.
__global__ void __launch_bounds__(256, 2) k_lstm(
    const bf16* __restrict__ Uhi, const bf16* __restrict__ Ulo,
    const bf16* __restrict__ Whi, const bf16* __restrict__ Wlo,
    const float* __restrict__ b_ih, const float* __restrict__ b_hh,
    const float* __restrict__ c0, float* __restrict__ h_out,
    float* __restrict__ c_out) {
  __shared__ char lds[32768];  // Ahi 0 | Alo 8K | Bhi 16K | Blo 24K, each 128x32 bf16
  const int tid = threadIdx.x;
  const int l = tid & 63;
  const int w = tid >> 6;

  // XCD-aware swizzle (1024 blocks, 1024 % 8 == 0 -> bijective)
  int bid = blockIdx.x;
  int swz = (bid & 7) * 128 + (bid >> 3);
  const int bm = swz >> 5;   // 0..31: M block (128 rows)
  const int bn = swz & 31;   // 0..31: h-col block (32 cols)
  const int rowBase = bm * 128;
  const int hcBase = bn * 32;

  // ---- staging constants (global_load_lds, width 16B) ----
  // lane l of wave w, inst j: LDS tile byte (w*2+j)*1024 + l*16
  //   -> tile row (w*32 + 16j + l/4), 16B-slot (l&3)
  // pre-swizzled source: global kgroup = slot ^ (row & 3)
  const int srow0 = w * 32 + (l >> 2);
  const int srow1 = srow0 + 16;
  const int kg = ((l >> 2) & 3) ^ (l & 3);
  const size_t aoff0 = (size_t)(rowBase + srow0) * TK + kg * 8;
  const size_t aoff1 = aoff0 + (size_t)16 * TK;
  // B tile row rt maps to W row (rt>>5)*1024 + hcBase + (rt&31)
  const int br0 = ((srow0 >> 5) << 10) + hcBase + (srow0 & 31);
  const int br1 = ((srow1 >> 5) << 10) + hcBase + (srow1 & 31);
  const size_t boff0 = (size_t)br0 * TK + kg * 8;
  const size_t boff1 = (size_t)br1 * TK + kg * 8;

  char* wj0 = lds + (w * 2) * 1024;
  char* wj1 = wj0 + 1024;

  // ---- fragment read offsets (swizzle baked in; row&3 == l&3) ----
  const int laneRB = (l & 15) * 64 + (((l >> 4) ^ (l & 3)) << 4);
  const int aO0 = (w * 32) * 64 + laneRB;  // m=0
  const int aO1 = aO0 + 1024;              // m=1 (+16 rows)

  f32x4 acc[2][8] = {};  // [m][n], n = gate q*2 + n0

  for (int kt = 0; kt < KSTEPS; ++kt) {
    const int k0 = kt * 32;
    gload16(Uhi + aoff0 + k0, wj0);
    gload16(Uhi + aoff1 + k0, wj1);
    gload16(Ulo + aoff0 + k0, wj0 + 8192);
    gload16(Ulo + aoff1 + k0, wj1 + 8192);
    gload16(Whi + boff0 + k0, wj0 + 16384);
    gload16(Whi + boff1 + k0, wj1 + 16384);
    gload16(Wlo + boff0 + k0, wj0 + 24576);
    gload16(Wlo + boff1 + k0, wj1 + 24576);
    __syncthreads();  // drains vmcnt before barrier (compiler-inserted)

    bf16x8 ah0 = *(const bf16x8*)(lds + aO0);
    bf16x8 ah1 = *(const bf16x8*)(lds + aO1);
    bf16x8 al0 = *(const bf16x8*)(lds + 8192 + aO0);
    bf16x8 al1 = *(const bf16x8*)(lds + 8192 + aO1);
#pragma unroll
    for (int n = 0; n < 8; ++n) {
      bf16x8 bh = *(const bf16x8*)(lds + 16384 + n * 1024 + laneRB);
      bf16x8 bl = *(const bf16x8*)(lds + 24576 + n * 1024 + laneRB);
      // acc += Ahi*Bhi + Ahi*Blo + Alo*Bhi   (bf16x3 ~ fp32 accuracy)
      acc[0][n] = __builtin_amdgcn_mfma_f32_16x16x32_bf16(ah0, bh, acc[0][n], 0, 0, 0);
      acc[1][n] = __builtin_amdgcn_mfma_f32_16x16x32_bf16(ah1, bh, acc[1][n], 0, 0, 0);
      acc[0][n] = __builtin_amdgcn_mfma_f32_16x16x32_bf16(ah0, bl, acc[0][n], 0, 0, 0);
      acc[1][n] = __builtin_amdgcn_mfma_f32_16x16x32_bf16(ah1, bl, acc[1][n], 0, 0, 0);
      acc[0][n] = __builtin_amdgcn_mfma_f32_16x16x32_bf16(al0, bh, acc[0][n], 0, 0, 0);
      acc[1][n] = __builtin_amdgcn_mfma_f32_16x16x32_bf16(al1, bh, acc[1][n], 0, 0, 0);
    }
    __syncthreads();
  }

  // ---- in-register LSTM epilogue ----
  // C/D layout (m89-verified): col = l&15, row = (l>>4)*4 + r
  const int cl = l & 15;
  const int rsub = (l >> 4) * 4;
#pragma unroll
  for (int n0 = 0; n0 < 2; ++n0) {
    const int hc = hcBase + n0 * 16 + cl;
    const float bi = b_ih[hc] + b_hh[hc];
    const float bfv = b_ih[TH + hc] + b_hh[TH + hc];
    const float bg = b_ih[2 * TH + hc] + b_hh[2 * TH + hc];
    const float bo = b_ih[3 * TH + hc] + b_hh[3 * TH + hc];
#pragma unroll
    for (int m = 0; m < 2; ++m) {
#pragma unroll
      for (int r = 0; r < 4; ++r) {
        const int row = rowBase + w * 32 + m * 16 + rsub + r;
        float gi = acc[m][n0 + 0][r] + bi;
        float gf = acc[m][n0 + 2][r] + bfv;
        float gg = acc[m][n0 + 4][r] + bg;
        float go = acc[m][n0 + 6][r] + bo;
        float cprev = c0[(size_t)row * TH + hc];
        float ig = 1.0f / (1.0f + __expf(-gi));
        float fg = 1.0f / (1.0f + __expf(-gf));
        float og = 1.0f / (1.0f + __expf(-go));
        float cn = fg * cprev + ig * tanhf(gg);
        float hn = og * tanhf(cn);
        h_out[(size_t)row * TH + hc] = hn;
        c_out[(size_t)row * TH + hc] = cn;
      }
    }
  }
}

extern "C" void kernel_launch(void* const* d_in, const int* in_sizes, int n_in,
                              void* d_out, int out_size, void* d_ws, size_t ws_size,
                              hipStream_t stream) {
  const float* x    = (const float*)d_in[0];
  const float* h0   = (const float*)d_in[1];
  const float* c0   = (const float*)d_in[2];
  const float* w_ih = (const float*)d_in[3];
  const float* w_hh = (const float*)d_in[4];
  const float* b_ih = (const float*)d_in[5];
  const float* b_hh = (const float*)d_in[6];

  float* h_out = (float*)d_out;                    // reference returns (h, c)
  float* c_out = h_out + (size_t)TB * TH;

  // workspace: Uhi | Ulo | Whi | Wlo, each 4096x2048 bf16 (16 MB) = 64 MB total
  bf16* Uhi = (bf16*)d_ws;
  bf16* Ulo = Uhi + (size_t)TB * TK;
  bf16* Whi = Ulo + (size_t)TB * TK;
  bf16* Wlo = Whi + (size_t)TB * TK;

  const int convBlocks = (2 * TB * TK / 4) / 256;  // 16384
  k_convert<<<convBlocks, 256, 0, stream>>>(x, h0, w_ih, w_hh, Uhi, Ulo, Whi, Wlo);
  k_lstm<<<1024, 256, 0, stream>>>(Uhi, Ulo, Whi, Wlo, b_ih, b_hh, c0, h_out, c_out);
}

// Round 3
// 239.886 us; speedup vs baseline: 1.4106x; 1.4106x over previous
//
#include <hip/hip_runtime.h>
#include <hip/hip_bf16.h>

// Problem: B=4096, D=1024, H=1024. Single LSTM cell step.
// gates[B][4H] = [x|h] @ [w_ih|w_hh]^T + (b_ih+b_hh); then pointwise.
#define TB 4096
#define TD 1024
#define TH 1024
#define TK 2048   // D + H
#define KSTEPS 32 // TK / 64

typedef _Float16 f16;
typedef _Float16 f16x8 __attribute__((ext_vector_type(8)));
typedef _Float16 f16x4 __attribute__((ext_vector_type(4)));
typedef float f32x4 __attribute__((ext_vector_type(4)));

__device__ __forceinline__ void gload16(const void* g, void* l) {
  __builtin_amdgcn_global_load_lds(
      (const __attribute__((address_space(1))) void*)g,
      (__attribute__((address_space(3))) void*)l, 16, 0, 0);
}

// fp32 -> fp16 for U=[x|h] (4096x2048) and W=[w_ih|w_hh] (4096x2048).
// fp16 (11 mantissa bits) single-pass: gate error ~5e-4, well inside the
// passing envelope (bf16x3 passed at absmax 0.0156).
__global__ void __launch_bounds__(256) k_convert(
    const float* __restrict__ x, const float* __restrict__ h0,
    const float* __restrict__ w_ih, const float* __restrict__ w_hh,
    f16* __restrict__ Uh, f16* __restrict__ Wh) {
  int t = blockIdx.x * 256 + threadIdx.x;
  const int perMat = (TB * TK) / 4;  // 2,097,152 threads per matrix
  const bool isW = t >= perMat;
  int tt = isW ? t - perMat : t;
  size_t e0 = (size_t)tt * 4;
  int row = (int)(e0 >> 11);
  int k = (int)(e0 & (TK - 1));
  const float* src;
  if (!isW)
    src = (k < TD) ? (x + (size_t)row * TD + k) : (h0 + (size_t)row * TH + (k - TD));
  else
    src = (k < TD) ? (w_ih + (size_t)row * TD + k) : (w_hh + (size_t)row * TH + (k - TD));
  float4 v = *(const float4*)src;
  f16x4 o;
  o[0] = (f16)v.x; o[1] = (f16)v.y; o[2] = (f16)v.z; o[3] = (f16)v.w;
  *(f16x4*)((isW ? Wh : Uh) + e0) = o;
}

// Fused fp16 GEMM + LSTM pointwise. Block tile: 128 U-rows x 32 h-cols
// (= 128 gate-cols: 4 strips of 32). Wave w owns rows [w*32, w*32+32).
// BK=64 (rows are 128B = exact 32-bank wrap) with full slot^(row&7) XOR
// swizzle -> 2-way bank access on ds_read_b128 (free, m136).
__global__ void __launch_bounds__(256) k_lstm(
    const f16* __restrict__ Uh, const f16* __restrict__ Wh,
    const float* __restrict__ b_ih, const float* __restrict__ b_hh,
    const float* __restrict__ c0, float* __restrict__ h_out,
    float* __restrict__ c_out) {
  __shared__ char lds[32768];  // A[128][64] f16 @0 (16K), B[128][64] f16 @16K
  const int tid = threadIdx.x;
  const int l = tid & 63;
  const int w = tid >> 6;

  // XCD-aware swizzle (1024 blocks % 8 == 0 -> bijective)
  int bid = blockIdx.x;
  int swz = (bid & 7) * 128 + (bid >> 3);
  const int bm = swz >> 5;
  const int bn = swz & 31;
  const int rowBase = bm * 128;
  const int hcBase = bn * 32;

  // ---- staging (global_load_lds w16). Inst j covers 8 rows (1KB).
  // lane l -> tile row (w*32 + j*8 + l/8), phys 16B-slot (l&7).
  // Phys slot t holds logical k-group t ^ (row&7); row&7 == l>>3.
  const int srow = l >> 3;
  const int g = (l & 7) ^ srow;  // pre-swizzled global k-group
  size_t aoff[4], boff[4];
#pragma unroll
  for (int j = 0; j < 4; ++j) {
    int rt = w * 32 + j * 8 + srow;
    aoff[j] = (size_t)(rowBase + rt) * TK + g * 8;
    int wr = ((rt >> 5) << 10) + hcBase + (rt & 31);  // gate-strip row -> W row
    boff[j] = (size_t)wr * TK + g * 8;
  }

  // ---- fragment read offsets (swizzle baked in; row&7 == fr&7) ----
  const int fr = l & 15;
  const int fq = l >> 4;  // 0..3
  const int s0 = ((fq ^ (fr & 7)) << 4);        // kk=0 slot byte
  const int s1 = (((4 + fq) ^ (fr & 7)) << 4);  // kk=1 slot byte
  const int aRow = (w * 32 + fr) * 128;

  f32x4 acc[2][8] = {};  // [m][n]; gate q lives at n = n0 + 2q

  for (int kt = 0; kt < KSTEPS; ++kt) {
    const size_t k0 = (size_t)kt * 64;
#pragma unroll
    for (int j = 0; j < 4; ++j)
      gload16(Uh + aoff[j] + k0, lds + w * 4096 + j * 1024);
#pragma unroll
    for (int j = 0; j < 4; ++j)
      gload16(Wh + boff[j] + k0, lds + 16384 + w * 4096 + j * 1024);
    __syncthreads();

    f16x8 a[2][2];
#pragma unroll
    for (int m = 0; m < 2; ++m) {
      a[m][0] = *(const f16x8*)(lds + aRow + m * 2048 + s0);
      a[m][1] = *(const f16x8*)(lds + aRow + m * 2048 + s1);
    }
#pragma unroll
    for (int n = 0; n < 8; ++n) {
      const int bRow = 16384 + (n * 16 + fr) * 128;
      f16x8 b0 = *(const f16x8*)(lds + bRow + s0);
      f16x8 b1 = *(const f16x8*)(lds + bRow + s1);
      acc[0][n] = __builtin_amdgcn_mfma_f32_16x16x32_f16(a[0][0], b0, acc[0][n], 0, 0, 0);
      acc[1][n] = __builtin_amdgcn_mfma_f32_16x16x32_f16(a[1][0], b0, acc[1][n], 0, 0, 0);
      acc[0][n] = __builtin_amdgcn_mfma_f32_16x16x32_f16(a[0][1], b1, acc[0][n], 0, 0, 0);
      acc[1][n] = __builtin_amdgcn_mfma_f32_16x16x32_f16(a[1][1], b1, acc[1][n], 0, 0, 0);
    }
    __syncthreads();
  }

  // ---- in-register LSTM epilogue ----
  // C/D layout (m89, HW-verified in Round 0): col = l&15, row = (l>>4)*4 + r
  const int cl = l & 15;
  const int rsub = fq * 4;
#pragma unroll
  for (int n0 = 0; n0 < 2; ++n0) {
    const int hc = hcBase + n0 * 16 + cl;
    const float bi = b_ih[hc] + b_hh[hc];
    const float bfv = b_ih[TH + hc] + b_hh[TH + hc];
    const float bg = b_ih[2 * TH + hc] + b_hh[2 * TH + hc];
    const float bo = b_ih[3 * TH + hc] + b_hh[3 * TH + hc];
#pragma unroll
    for (int m = 0; m < 2; ++m) {
#pragma unroll
      for (int r = 0; r < 4; ++r) {
        const int row = rowBase + w * 32 + m * 16 + rsub + r;
        float gi = acc[m][n0 + 0][r] + bi;
        float gf = acc[m][n0 + 2][r] + bfv;
        float gg = acc[m][n0 + 4][r] + bg;
        float go = acc[m][n0 + 6][r] + bo;
        float cprev = c0[(size_t)row * TH + hc];
        float ig = 1.0f / (1.0f + __expf(-gi));
        float fg = 1.0f / (1.0f + __expf(-gf));
        float og = 1.0f / (1.0f + __expf(-go));
        float cn = fg * cprev + ig * tanhf(gg);
        float hn = og * tanhf(cn);
        h_out[(size_t)row * TH + hc] = hn;
        c_out[(size_t)row * TH + hc] = cn;
      }
    }
  }
}

extern "C" void kernel_launch(void* const* d_in, const int* in_sizes, int n_in,
                              void* d_out, int out_size, void* d_ws, size_t ws_size,
                              hipStream_t stream) {
  const float* x    = (const float*)d_in[0];
  const float* h0   = (const float*)d_in[1];
  const float* c0   = (const float*)d_in[2];
  const float* w_ih = (const float*)d_in[3];
  const float* w_hh = (const float*)d_in[4];
  const float* b_ih = (const float*)d_in[5];
  const float* b_hh = (const float*)d_in[6];

  float* h_out = (float*)d_out;  // reference returns (h, c) concatenated
  float* c_out = h_out + (size_t)TB * TH;

  // workspace: Uh | Wh, each 4096x2048 f16 (16 MB) = 32 MB
  f16* Uh = (f16*)d_ws;
  f16* Wh = Uh + (size_t)TB * TK;

  const int convBlocks = (2 * TB * TK / 4) / 256;  // 16384
  k_convert<<<convBlocks, 256, 0, stream>>>(x, h0, w_ih, w_hh, Uh, Wh);
  k_lstm<<<1024, 256, 0, stream>>>(Uh, Wh, b_ih, b_hh, c0, h_out, c_out);
}

// Round 4
// 211.469 us; speedup vs baseline: 1.6001x; 1.1344x over previous
//
#include <hip/hip_runtime.h>
#include <hip/hip_bf16.h>

// B=4096, D=1024, H=1024. gates[B][4H] = [x|h]@[w_ih|w_hh]^T + b; pointwise.
#define TB 4096
#define TD 1024
#define TH 1024
#define TK 2048
#define NT 64           // K-tiles of BK=32
#define BUF_SZ 32768    // per K-tile: A 16KB + B 16KB
#define B_OFF 16384

typedef _Float16 f16;
typedef _Float16 f16x8 __attribute__((ext_vector_type(8)));
typedef _Float16 f16x4 __attribute__((ext_vector_type(4)));
typedef float f32x4 __attribute__((ext_vector_type(4)));

__device__ __forceinline__ void gload16(const f16* g, const char* l) {
  __builtin_amdgcn_global_load_lds(
      (const __attribute__((address_space(1))) void*)g,
      (__attribute__((address_space(3))) void*)l, 16, 0, 0);
}

// fp32 -> fp16 for U=[x|h] and W=[w_ih|w_hh] (each 4096x2048).
__global__ void __launch_bounds__(256) k_convert(
    const float* __restrict__ x, const float* __restrict__ h0,
    const float* __restrict__ w_ih, const float* __restrict__ w_hh,
    f16* __restrict__ Uh, f16* __restrict__ Wh) {
  int t = blockIdx.x * 256 + threadIdx.x;
  const int perMat = (TB * TK) / 4;
  const bool isW = t >= perMat;
  int tt = isW ? t - perMat : t;
  size_t e0 = (size_t)tt * 4;
  int row = (int)(e0 >> 11);
  int k = (int)(e0 & (TK - 1));
  const float* src;
  if (!isW)
    src = (k < TD) ? (x + (size_t)row * TD + k) : (h0 + (size_t)row * TH + (k - TD));
  else
    src = (k < TD) ? (w_ih + (size_t)row * TD + k) : (w_hh + (size_t)row * TH + (k - TD));
  float4 v = *(const float4*)src;
  f16x4 o;
  o[0] = (f16)v.x; o[1] = (f16)v.y; o[2] = (f16)v.z; o[3] = (f16)v.w;
  *(f16x4*)((isW ? Wh : Uh) + e0) = o;
}

// 256x256 tile, BK=32, 8 waves (2M x 4N), 3-buffer LDS rotation (96KB),
// counted vmcnt(4), raw s_barrier (1/body). Per-wave output 128x64 =
// 8 m-frags x 4 n-frags where n-frag == gate (i,f,g,o) for h-cols
// hcBase + wc*16 .. +16 -> in-register LSTM epilogue.
__global__ void __launch_bounds__(512, 2) k_lstm(
    const f16* __restrict__ Uh, const f16* __restrict__ Wh,
    const float* __restrict__ b_ih, const float* __restrict__ b_hh,
    const float* __restrict__ c0, float* __restrict__ h_out,
    float* __restrict__ c_out) {
  extern __shared__ char lds[];  // 3 * 32KB
  const int tid = threadIdx.x;
  const int l = tid & 63;
  const int w = tid >> 6;        // 0..7
  const int wm = w >> 2;         // 0..1: M half (128 rows)
  const int wc = w & 3;          // 0..3: N quarter (64 gate-cols)

  // XCD-aware swizzle (256 blocks % 8 == 0, bijective). Chunk = 2 bm x 16 bn.
  int bid = blockIdx.x;
  int swz = (bid & 7) * 32 + (bid >> 3);
  const int bm = swz >> 4;       // 0..15
  const int bn = swz & 15;       // 0..15
  const int rowBase = bm * 256;
  const int hcBase = bn * 64;

  // ---- staging constants. Chunk c (0..15) = 16 tile-rows -> LDS c*1024.
  // Lane l: row c*16 + (l>>2), phys 16B-slot (l&3) holding logical k-group
  // g = (l&3) ^ ((row>>1)&3) = (l&3) ^ ((l>>3)&3)  [2-way bank access: free].
  const int g = (l & 3) ^ ((l >> 3) & 3);
  const int rl = l >> 2;         // 0..15
  const int cA0 = w, cA1 = 8 + w;
  const f16* aP0 = Uh + (size_t)(rowBase + cA0 * 16 + rl) * TK + g * 8;
  const f16* aP1 = Uh + (size_t)(rowBase + cA1 * 16 + rl) * TK + g * 8;
  // B tile row j (0..255) -> W row ((j>>4)&3)*1024 + hcBase + (j&15) + (j>>6)*16
  const f16* bP0 = Wh + (size_t)((cA0 & 3) * 1024 + hcBase + rl + (cA0 >> 2) * 16) * TK + g * 8;
  const f16* bP1 = Wh + (size_t)((cA1 & 3) * 1024 + hcBase + rl + (cA1 >> 2) * 16) * TK + g * 8;

  // ---- fragment read offsets (row = 64B; swizzle: phys slot = fq ^ ((row>>1)&3))
  const int fr = l & 15;
  const int fq = l >> 4;
  const int slot = ((fq ^ ((fr >> 1) & 3)) << 4);
  const int aAddr = (wm * 128 + fr) * 64 + slot;         // + buf + m*1024
  const int bAddr = B_OFF + (wc * 64 + fr) * 64 + slot;  // + buf + n*1024

  f32x4 acc[8][4] = {};  // [m][n]; n = gate index

  // ---- prologue: tile0 -> buf0, tile1 -> buf1; wait tile0; barrier
  gload16(aP0, lds + 0 * BUF_SZ + cA0 * 1024);
  gload16(aP1, lds + 0 * BUF_SZ + cA1 * 1024);
  gload16(bP0, lds + 0 * BUF_SZ + B_OFF + cA0 * 1024);
  gload16(bP1, lds + 0 * BUF_SZ + B_OFF + cA1 * 1024);
  gload16(aP0 + 32, lds + 1 * BUF_SZ + cA0 * 1024);
  gload16(aP1 + 32, lds + 1 * BUF_SZ + cA1 * 1024);
  gload16(bP0 + 32, lds + 1 * BUF_SZ + B_OFF + cA0 * 1024);
  gload16(bP1 + 32, lds + 1 * BUF_SZ + B_OFF + cA1 * 1024);
  asm volatile("s_waitcnt vmcnt(4)" ::: "memory");
  __builtin_amdgcn_sched_barrier(0);
  __builtin_amdgcn_s_barrier();

  int offR = 0;            // read buf byte-offset  (t%3)
  int offS = 2 * BUF_SZ;   // stage buf byte-offset ((t+2)%3)
  for (int t = 0; t < NT; ++t) {
    // stage tile t+2 -> buf[(t+2)%3]; dest held tile t-1, consumed pre-barrier
    if (t < NT - 2) {
      const int ke = (t + 2) * 32;
      gload16(aP0 + ke, lds + offS + cA0 * 1024);
      gload16(aP1 + ke, lds + offS + cA1 * 1024);
      gload16(bP0 + ke, lds + offS + B_OFF + cA0 * 1024);
      gload16(bP1 + ke, lds + offS + B_OFF + cA1 * 1024);
    }
    const char* baseA = lds + offR + aAddr;
    const char* baseB = lds + offR + bAddr;
    f16x8 af[8], bf[4];
#pragma unroll
    for (int m = 0; m < 8; ++m) af[m] = *(const f16x8*)(baseA + m * 1024);
#pragma unroll
    for (int n = 0; n < 4; ++n) bf[n] = *(const f16x8*)(baseB + n * 1024);
    __builtin_amdgcn_s_setprio(1);
#pragma unroll
    for (int m = 0; m < 8; ++m)
#pragma unroll
      for (int n = 0; n < 4; ++n)
        acc[m][n] = __builtin_amdgcn_mfma_f32_16x16x32_f16(af[m], bf[n], acc[m][n], 0, 0, 0);
    __builtin_amdgcn_s_setprio(0);
    // pin: reads complete + tile t+1 landed, then barrier (rule 18: sched_barrier)
    asm volatile("s_waitcnt lgkmcnt(0)" ::: "memory");
    if (t < NT - 2)
      asm volatile("s_waitcnt vmcnt(4)" ::: "memory");  // drains tile t+1; t+2 in flight
    else
      asm volatile("s_waitcnt vmcnt(0)" ::: "memory");  // tail: nothing newer issued
    __builtin_amdgcn_sched_barrier(0);
    __builtin_amdgcn_s_barrier();
    offR = (offR == 2 * BUF_SZ) ? 0 : offR + BUF_SZ;
    offS = (offS == 2 * BUF_SZ) ? 0 : offS + BUF_SZ;
  }

  // ---- in-register LSTM epilogue (C/D: col = l&15, row = fq*4 + r; m89)
  const int hc = hcBase + wc * 16 + fr;
  const float bi = b_ih[hc] + b_hh[hc];
  const float bfv = b_ih[TH + hc] + b_hh[TH + hc];
  const float bg = b_ih[2 * TH + hc] + b_hh[2 * TH + hc];
  const float bo = b_ih[3 * TH + hc] + b_hh[3 * TH + hc];
#pragma unroll
  for (int m = 0; m < 8; ++m) {
#pragma unroll
    for (int r = 0; r < 4; ++r) {
      const int row = rowBase + wm * 128 + m * 16 + fq * 4 + r;
      float gi = acc[m][0][r] + bi;
      float gf = acc[m][1][r] + bfv;
      float gg = acc[m][2][r] + bg;
      float go = acc[m][3][r] + bo;
      float cprev = c0[(size_t)row * TH + hc];
      float ig = 1.0f / (1.0f + __expf(-gi));
      float fg = 1.0f / (1.0f + __expf(-gf));
      float og = 1.0f / (1.0f + __expf(-go));
      float cn = fg * cprev + ig * tanhf(gg);
      float hn = og * tanhf(cn);
      h_out[(size_t)row * TH + hc] = hn;
      c_out[(size_t)row * TH + hc] = cn;
    }
  }
}

extern "C" void kernel_launch(void* const* d_in, const int* in_sizes, int n_in,
                              void* d_out, int out_size, void* d_ws, size_t ws_size,
                              hipStream_t stream) {
  const float* x    = (const float*)d_in[0];
  const float* h0   = (const float*)d_in[1];
  const float* c0   = (const float*)d_in[2];
  const float* w_ih = (const float*)d_in[3];
  const float* w_hh = (const float*)d_in[4];
  const float* b_ih = (const float*)d_in[5];
  const float* b_hh = (const float*)d_in[6];

  float* h_out = (float*)d_out;
  float* c_out = h_out + (size_t)TB * TH;

  f16* Uh = (f16*)d_ws;
  f16* Wh = Uh + (size_t)TB * TK;

  const int convBlocks = (2 * TB * TK / 4) / 256;  // 16384
  k_convert<<<convBlocks, 256, 0, stream>>>(x, h0, w_ih, w_hh, Uh, Wh);

  static_assert(3 * BUF_SZ == 98304, "lds");
  (void)hipFuncSetAttribute((const void*)k_lstm,
                            hipFuncAttributeMaxDynamicSharedMemorySize, 3 * BUF_SZ);
  k_lstm<<<256, 512, 3 * BUF_SZ, stream>>>(Uh, Wh, b_ih, b_hh, c0, h_out, c_out);
}

// Round 5
// 210.976 us; speedup vs baseline: 1.6039x; 1.0023x over previous
//
#include <hip/hip_runtime.h>
#include <hip/hip_bf16.h>

// B=4096, D=1024, H=1024. gates[B][4H] = [x|h]@[w_ih|w_hh]^T + b; pointwise.
#define TB 4096
#define TD 1024
#define TH 1024
#define TK 2048
#define NITER 16   // 2 K-tiles (BK=64) per iter, 32 tiles total

typedef _Float16 f16;
typedef _Float16 f16x8 __attribute__((ext_vector_type(8)));
typedef _Float16 f16x4 __attribute__((ext_vector_type(4)));
typedef float f32x4 __attribute__((ext_vector_type(4)));

__device__ __forceinline__ void gload16(const f16* g, const char* l) {
  __builtin_amdgcn_global_load_lds(
      (const __attribute__((address_space(1))) void*)g,
      (__attribute__((address_space(3))) void*)l, 16, 0, 0);
}

// fp32 -> fp16 for U=[x|h] and W=[w_ih|w_hh] (each 4096x2048).
__global__ void __launch_bounds__(256) k_convert(
    const float* __restrict__ x, const float* __restrict__ h0,
    const float* __restrict__ w_ih, const float* __restrict__ w_hh,
    f16* __restrict__ Uh, f16* __restrict__ Wh) {
  int t = blockIdx.x * 256 + threadIdx.x;
  const int perMat = (TB * TK) / 4;
  const bool isW = t >= perMat;
  int tt = isW ? t - perMat : t;
  size_t e0 = (size_t)tt * 4;
  int row = (int)(e0 >> 11);
  int k = (int)(e0 & (TK - 1));
  const float* src;
  if (!isW)
    src = (k < TD) ? (x + (size_t)row * TD + k) : (h0 + (size_t)row * TH + (k - TD));
  else
    src = (k < TD) ? (w_ih + (size_t)row * TD + k) : (w_hh + (size_t)row * TH + (k - TD));
  float4 v = *(const float4*)src;
  f16x4 o;
  o[0] = (f16)v.x; o[1] = (f16)v.y; o[2] = (f16)v.z; o[3] = (f16)v.w;
  *(f16x4*)((isW ? Wh : Uh) + e0) = o;
}

// One phase: ds_read A-quad (+B quad on even phases), stage one 16KB sub-tile,
// barrier, lgkm(0), setprio'd 16 MFMA, [vmcnt(8) guard], barrier.
#define PH(RB, MQ, LOADB, SP0, SP1, SD, KOFF, PRED, VM)                          \
  {                                                                              \
    if (LOADB) {                                                                 \
      _Pragma("unroll") for (int n = 0; n < 4; ++n)                              \
          bf[n] = *(const f16x8*)(lds + (RB) + 16384 + bOff + n * 1024);         \
    }                                                                            \
    f16x8 af[4];                                                                 \
    _Pragma("unroll") for (int m = 0; m < 4; ++m)                                \
        af[m] = *(const f16x8*)(lds + (RB) + aOff + ((MQ) * 4 + m) * 1024);      \
    if (PRED) {                                                                  \
      gload16((SP0) + (KOFF), (SD));                                             \
      gload16((SP1) + (KOFF), (SD) + 8192);                                      \
    }                                                                            \
    __builtin_amdgcn_s_barrier();                                                \
    asm volatile("s_waitcnt lgkmcnt(0)" ::: "memory");                           \
    __builtin_amdgcn_sched_barrier(0);                                           \
    __builtin_amdgcn_s_setprio(1);                                               \
    _Pragma("unroll") for (int m = 0; m < 4; ++m)                                \
        _Pragma("unroll") for (int n = 0; n < 4; ++n)                            \
            acc[(MQ) * 4 + m][n] = __builtin_amdgcn_mfma_f32_16x16x32_f16(       \
                af[m], bf[n], acc[(MQ) * 4 + m][n], 0, 0, 0);                    \
    __builtin_amdgcn_s_setprio(0);                                               \
    if (VM) {                                                                    \
      asm volatile("s_waitcnt vmcnt(8)" ::: "memory");                           \
      __builtin_amdgcn_sched_barrier(0);                                         \
    }                                                                            \
    __builtin_amdgcn_s_barrier();                                                \
  }

// 256x256 tile, BK=64, 8 waves (2Mx4N), m201-style 8-phase schedule.
// LDS 128KB: dbuf[2] x K-tile, each tile = {Ak0,Bk0,Ak1,Bk1} 16KB sub-tiles
// ([256 rows][32 f16], 64B rows, phys slot = fq ^ ((row>>1)&3) -> 2-way free).
// Even tiles -> dbuf0, odd -> dbuf1. Stage stream (iter i, T0=2i..T3=2i+3):
//   p0:T1.Ak1 p1:T1.Bk1 p2:T2.Ak0 p3:T2.Bk0 p4:T2.Ak1 p5:T2.Bk1 p6:T3.Ak0 p7:T3.Bk0
// vmcnt(8) at p1/p3/p5/p7 guards the next even phase's fresh sub-tile reads
// (4 sub-tiles = 8 loads always in flight; guarded data issued 4-6 phases ago).
__global__ void __launch_bounds__(512, 2) k_lstm(
    const f16* __restrict__ Uh, const f16* __restrict__ Wh,
    const float* __restrict__ b_ih, const float* __restrict__ b_hh,
    const float* __restrict__ c0, float* __restrict__ h_out,
    float* __restrict__ c_out) {
  extern __shared__ char lds[];  // 2 x 64KB
  const int tid = threadIdx.x;
  const int l = tid & 63;
  const int w = tid >> 6;        // 0..7
  const int wm = w >> 2;         // M half (128 rows)
  const int wc = w & 3;          // N quarter (16 h-cols x 4 gates)

  // XCD-aware swizzle (256 blocks % 8 == 0, bijective)
  int bid = blockIdx.x;
  int swz = (bid & 7) * 32 + (bid >> 3);
  const int bm = swz >> 4;
  const int bn = swz & 15;
  const int rowBase = bm * 256;
  const int hcBase = bn * 64;

  // ---- staging constants (validated in r3/r4): chunk c = 16 rows of 64B;
  // lane l: row c*16 + (l>>2), phys slot l&3, logical k-group g = (l&3)^((l>>3)&3)
  const int rl = l >> 2;
  const int g = (l & 3) ^ ((l >> 3) & 3);
  const int c0i = w, c1i = w + 8;
  const f16* aP0 = Uh + (size_t)(rowBase + c0i * 16 + rl) * TK + g * 8;
  const f16* aP1 = Uh + (size_t)(rowBase + c1i * 16 + rl) * TK + g * 8;
  const f16* bP0 = Wh + (size_t)((c0i & 3) * 1024 + hcBase + rl + (c0i >> 2) * 16) * TK + g * 8;
  const f16* bP1 = Wh + (size_t)((c1i & 3) * 1024 + hcBase + rl + (c1i >> 2) * 16) * TK + g * 8;
  char* sdw = lds + w * 1024;  // + sub-tile base; +8192 for chunk c1

  // ---- fragment read offsets (validated in r3/r4)
  const int fr = l & 15;
  const int fq = l >> 4;
  const int slot = (fq ^ ((fr >> 1) & 3)) << 4;
  const int aOff = (wm * 128 + fr) * 64 + slot;
  const int bOff = (wc * 64 + fr) * 64 + slot;

  f32x4 acc[8][4] = {};  // [m][n]; n = gate
  f16x8 bf[4];           // B frags for current kk (persist even->odd phase)

  // ---- prologue: T0.{Ak0,Bk0,Ak1,Bk1}, T1.{Ak0,Bk0} (stream order)
  gload16(aP0 + 0,  sdw + 0);      gload16(aP1 + 0,  sdw + 0 + 8192);
  gload16(bP0 + 0,  sdw + 16384);  gload16(bP1 + 0,  sdw + 16384 + 8192);
  gload16(aP0 + 32, sdw + 32768);  gload16(aP1 + 32, sdw + 32768 + 8192);
  gload16(bP0 + 32, sdw + 49152);  gload16(bP1 + 32, sdw + 49152 + 8192);
  gload16(aP0 + 64, sdw + 65536);  gload16(aP1 + 64, sdw + 65536 + 8192);
  gload16(bP0 + 64, sdw + 81920);  gload16(bP1 + 64, sdw + 81920 + 8192);
  asm volatile("s_waitcnt vmcnt(8)" ::: "memory");  // T0.kk0 landed
  __builtin_amdgcn_sched_barrier(0);
  __builtin_amdgcn_s_barrier();

  for (int i = 0; i < NITER; ++i) {
    const int kb = i * 128;
    const bool pr = (i < NITER - 1);
    // T0=2i from dbuf0 (p0-3), T1=2i+1 from dbuf1 (p4-7)
    PH(0,     0, true,  aP0, aP1, sdw + 65536 + 32768, kb + 96,  true, false)  // st T1.Ak1
    PH(0,     1, false, bP0, bP1, sdw + 65536 + 49152, kb + 96,  true, true)   // st T1.Bk1
    PH(32768, 0, true,  aP0, aP1, sdw + 0,             kb + 128, pr,   false)  // st T2.Ak0
    PH(32768, 1, false, bP0, bP1, sdw + 16384,         kb + 128, pr,   true)   // st T2.Bk0
    PH(65536, 0, true,  aP0, aP1, sdw + 32768,         kb + 160, pr,   false)  // st T2.Ak1
    PH(65536, 1, false, bP0, bP1, sdw + 49152,         kb + 160, pr,   true)   // st T2.Bk1
    PH(98304, 0, true,  aP0, aP1, sdw + 65536,         kb + 192, pr,   false)  // st T3.Ak0
    PH(98304, 1, false, bP0, bP1, sdw + 65536 + 16384, kb + 192, pr,   true)   // st T3.Bk0
  }

  // ---- in-register LSTM epilogue (C/D: col = l&15, row = fq*4 + r; validated)
  const int hc = hcBase + wc * 16 + fr;
  const float bi = b_ih[hc] + b_hh[hc];
  const float bfv = b_ih[TH + hc] + b_hh[TH + hc];
  const float bg = b_ih[2 * TH + hc] + b_hh[2 * TH + hc];
  const float bo = b_ih[3 * TH + hc] + b_hh[3 * TH + hc];
#pragma unroll
  for (int m = 0; m < 8; ++m) {
#pragma unroll
    for (int r = 0; r < 4; ++r) {
      const int row = rowBase + wm * 128 + m * 16 + fq * 4 + r;
      float gi = acc[m][0][r] + bi;
      float gf = acc[m][1][r] + bfv;
      float gg = acc[m][2][r] + bg;
      float go = acc[m][3][r] + bo;
      float cprev = c0[(size_t)row * TH + hc];
      float ig = 1.0f / (1.0f + __expf(-gi));
      float fg = 1.0f / (1.0f + __expf(-gf));
      float og = 1.0f / (1.0f + __expf(-go));
      float cn = fg * cprev + ig * tanhf(gg);
      float hn = og * tanhf(cn);
      h_out[(size_t)row * TH + hc] = hn;
      c_out[(size_t)row * TH + hc] = cn;
    }
  }
}

extern "C" void kernel_launch(void* const* d_in, const int* in_sizes, int n_in,
                              void* d_out, int out_size, void* d_ws, size_t ws_size,
                              hipStream_t stream) {
  const float* x    = (const float*)d_in[0];
  const float* h0   = (const float*)d_in[1];
  const float* c0   = (const float*)d_in[2];
  const float* w_ih = (const float*)d_in[3];
  const float* w_hh = (const float*)d_in[4];
  const float* b_ih = (const float*)d_in[5];
  const float* b_hh = (const float*)d_in[6];

  float* h_out = (float*)d_out;
  float* c_out = h_out + (size_t)TB * TH;

  f16* Uh = (f16*)d_ws;
  f16* Wh = Uh + (size_t)TB * TK;

  const int convBlocks = (2 * TB * TK / 4) / 256;  // 16384
  k_convert<<<convBlocks, 256, 0, stream>>>(x, h0, w_ih, w_hh, Uh, Wh);

  (void)hipFuncSetAttribute((const void*)k_lstm,
                            hipFuncAttributeMaxDynamicSharedMemorySize, 131072);
  k_lstm<<<256, 512, 131072, stream>>>(Uh, Wh, b_ih, b_hh, c0, h_out, c_out);
}

// Round 6
// 209.923 us; speedup vs baseline: 1.6119x; 1.0050x over previous
//
#include <hip/hip_runtime.h>
#include <hip/hip_bf16.h>

// B=4096, D=1024, H=1024. gates[B][4H] = [x|h]@[w_ih|w_hh]^T + b; pointwise.
#define TB 4096
#define TD 1024
#define TH 1024
#define TK 2048
#define NITER 16   // 2 K-tiles (BK=64) per iter, 32 tiles total

typedef _Float16 f16;
typedef _Float16 f16x8 __attribute__((ext_vector_type(8)));
typedef _Float16 f16x4 __attribute__((ext_vector_type(4)));
typedef float f32x4 __attribute__((ext_vector_type(4)));

__device__ __forceinline__ void gload16(const f16* g, const char* l) {
  __builtin_amdgcn_global_load_lds(
      (const __attribute__((address_space(1))) void*)g,
      (__attribute__((address_space(3))) void*)l, 16, 0, 0);
}

// fp32 -> fp16 for U=[x|h] and W=[w_ih|w_hh] (each 4096x2048).
__global__ void __launch_bounds__(256) k_convert(
    const float* __restrict__ x, const float* __restrict__ h0,
    const float* __restrict__ w_ih, const float* __restrict__ w_hh,
    f16* __restrict__ Uh, f16* __restrict__ Wh) {
  int t = blockIdx.x * 256 + threadIdx.x;
  const int perMat = (TB * TK) / 4;
  const bool isW = t >= perMat;
  int tt = isW ? t - perMat : t;
  size_t e0 = (size_t)tt * 4;
  int row = (int)(e0 >> 11);
  int k = (int)(e0 & (TK - 1));
  const float* src;
  if (!isW)
    src = (k < TD) ? (x + (size_t)row * TD + k) : (h0 + (size_t)row * TH + (k - TD));
  else
    src = (k < TD) ? (w_ih + (size_t)row * TD + k) : (w_hh + (size_t)row * TH + (k - TD));
  float4 v = *(const float4*)src;
  f16x4 o;
  o[0] = (f16)v.x; o[1] = (f16)v.y; o[2] = (f16)v.z; o[3] = (f16)v.w;
  *(f16x4*)((isW ? Wh : Uh) + e0) = o;
}

// One phase. KEY CHANGE vs r5: no lgkmcnt(0)+sched_barrier(0) before the
// MFMAs — plain LDS loads let the compiler emit fine-grained lgkmcnt so
// each MFMA waits only on its own frags (LDS pipe overlaps MFMA pipe).
// Residual lgkm drain AFTER the cluster preserves the read-before-restage
// barrier guarantee at ~zero cost.
#define PH(RB, MQ, LOADB, SP0, SP1, SD, KOFF, PRED, VM)                          \
  {                                                                              \
    if (LOADB) {                                                                 \
      _Pragma("unroll") for (int n = 0; n < 4; ++n)                              \
          bf[n] = *(const f16x8*)(lds + (RB) + 16384 + bOff + n * 1024);         \
    }                                                                            \
    f16x8 af[4];                                                                 \
    _Pragma("unroll") for (int m = 0; m < 4; ++m)                                \
        af[m] = *(const f16x8*)(lds + (RB) + aOff + ((MQ) * 4 + m) * 1024);      \
    if (PRED) {                                                                  \
      gload16((SP0) + (KOFF), (SD));                                             \
      gload16((SP1) + (KOFF), (SD) + 8192);                                      \
    }                                                                            \
    __builtin_amdgcn_s_barrier();                                                \
    __builtin_amdgcn_s_setprio(1);                                               \
    _Pragma("unroll") for (int m = 0; m < 4; ++m)                                \
        _Pragma("unroll") for (int n = 0; n < 4; ++n)                            \
            acc[(MQ) * 4 + m][n] = __builtin_amdgcn_mfma_f32_16x16x32_f16(       \
                af[m], bf[n], acc[(MQ) * 4 + m][n], 0, 0, 0);                    \
    __builtin_amdgcn_s_setprio(0);                                               \
    asm volatile("s_waitcnt lgkmcnt(0)" ::: "memory");                           \
    if (VM) {                                                                    \
      asm volatile("s_waitcnt vmcnt(8)" ::: "memory");                           \
    }                                                                            \
    __builtin_amdgcn_s_barrier();                                                \
  }

// 256x256 tile, BK=64, 8 waves (2Mx4N), m201-style 8-phase schedule.
// LDS 128KB: dbuf[2] x K-tile, each tile = {Ak0,Bk0,Ak1,Bk1} 16KB sub-tiles
// ([256 rows][32 f16], 64B rows, phys slot = fq ^ ((row>>1)&3) -> 2-way free).
// Stage stream (iter i, T0=2i..T3=2i+3):
//   p0:T1.Ak1 p1:T1.Bk1 p2:T2.Ak0 p3:T2.Bk0 p4:T2.Ak1 p5:T2.Bk1 p6:T3.Ak0 p7:T3.Bk0
// vmcnt(8) at p1/p3/p5/p7 guards the next even phase's fresh sub-tile reads
// (8 loads always in flight; guarded data issued 4-6 phases earlier).
__global__ void __launch_bounds__(512, 2) k_lstm(
    const f16* __restrict__ Uh, const f16* __restrict__ Wh,
    const float* __restrict__ b_ih, const float* __restrict__ b_hh,
    const float* __restrict__ c0, float* __restrict__ h_out,
    float* __restrict__ c_out) {
  extern __shared__ char lds[];  // 2 x 64KB
  const int tid = threadIdx.x;
  const int l = tid & 63;
  const int w = tid >> 6;        // 0..7
  const int wm = w >> 2;         // M half (128 rows)
  const int wc = w & 3;          // N quarter (16 h-cols x 4 gates)

  // XCD-aware swizzle (256 blocks % 8 == 0, bijective)
  int bid = blockIdx.x;
  int swz = (bid & 7) * 32 + (bid >> 3);
  const int bm = swz >> 4;
  const int bn = swz & 15;
  const int rowBase = bm * 256;
  const int hcBase = bn * 64;

  // ---- staging constants (validated r3-r5): chunk c = 16 rows of 64B;
  // lane l: row c*16 + (l>>2), phys slot l&3, logical k-group g = (l&3)^((l>>3)&3)
  const int rl = l >> 2;
  const int g = (l & 3) ^ ((l >> 3) & 3);
  const int c0i = w, c1i = w + 8;
  const f16* aP0 = Uh + (size_t)(rowBase + c0i * 16 + rl) * TK + g * 8;
  const f16* aP1 = Uh + (size_t)(rowBase + c1i * 16 + rl) * TK + g * 8;
  const f16* bP0 = Wh + (size_t)((c0i & 3) * 1024 + hcBase + rl + (c0i >> 2) * 16) * TK + g * 8;
  const f16* bP1 = Wh + (size_t)((c1i & 3) * 1024 + hcBase + rl + (c1i >> 2) * 16) * TK + g * 8;
  char* sdw = lds + w * 1024;  // + sub-tile base; +8192 for chunk c1

  // ---- fragment read offsets (validated r3-r5)
  const int fr = l & 15;
  const int fq = l >> 4;
  const int slot = (fq ^ ((fr >> 1) & 3)) << 4;
  const int aOff = (wm * 128 + fr) * 64 + slot;
  const int bOff = (wc * 64 + fr) * 64 + slot;

  f32x4 acc[8][4] = {};  // [m][n]; n = gate
  f16x8 bf[4];           // B frags for current kk (persist even->odd phase)

  // ---- prologue: T0.{Ak0,Bk0,Ak1,Bk1}, T1.{Ak0,Bk0} (stream order)
  gload16(aP0 + 0,  sdw + 0);      gload16(aP1 + 0,  sdw + 0 + 8192);
  gload16(bP0 + 0,  sdw + 16384);  gload16(bP1 + 0,  sdw + 16384 + 8192);
  gload16(aP0 + 32, sdw + 32768);  gload16(aP1 + 32, sdw + 32768 + 8192);
  gload16(bP0 + 32, sdw + 49152);  gload16(bP1 + 32, sdw + 49152 + 8192);
  gload16(aP0 + 64, sdw + 65536);  gload16(aP1 + 64, sdw + 65536 + 8192);
  gload16(bP0 + 64, sdw + 81920);  gload16(bP1 + 64, sdw + 81920 + 8192);
  asm volatile("s_waitcnt vmcnt(8)" ::: "memory");  // T0.kk0 landed
  __builtin_amdgcn_s_barrier();

  for (int i = 0; i < NITER; ++i) {
    const int kb = i * 128;
    const bool pr = (i < NITER - 1);
    // T0=2i from dbuf0 (p0-3), T1=2i+1 from dbuf1 (p4-7)
    PH(0,     0, true,  aP0, aP1, sdw + 65536 + 32768, kb + 96,  true, false)  // st T1.Ak1
    PH(0,     1, false, bP0, bP1, sdw + 65536 + 49152, kb + 96,  true, true)   // st T1.Bk1
    PH(32768, 0, true,  aP0, aP1, sdw + 0,             kb + 128, pr,   false)  // st T2.Ak0
    PH(32768, 1, false, bP0, bP1, sdw + 16384,         kb + 128, pr,   true)   // st T2.Bk0
    PH(65536, 0, true,  aP0, aP1, sdw + 32768,         kb + 160, pr,   false)  // st T2.Ak1
    PH(65536, 1, false, bP0, bP1, sdw + 49152,         kb + 160, pr,   true)   // st T2.Bk1
    PH(98304, 0, true,  aP0, aP1, sdw + 65536,         kb + 192, pr,   false)  // st T3.Ak0
    PH(98304, 1, false, bP0, bP1, sdw + 65536 + 16384, kb + 192, pr,   true)   // st T3.Bk0
  }

  // ---- in-register LSTM epilogue (C/D: col = l&15, row = fq*4 + r; validated)
  const int hc = hcBase + wc * 16 + fr;
  const float bi = b_ih[hc] + b_hh[hc];
  const float bfv = b_ih[TH + hc] + b_hh[TH + hc];
  const float bg = b_ih[2 * TH + hc] + b_hh[2 * TH + hc];
  const float bo = b_ih[3 * TH + hc] + b_hh[3 * TH + hc];
#pragma unroll
  for (int m = 0; m < 8; ++m) {
#pragma unroll
    for (int r = 0; r < 4; ++r) {
      const int row = rowBase + wm * 128 + m * 16 + fq * 4 + r;
      float gi = acc[m][0][r] + bi;
      float gf = acc[m][1][r] + bfv;
      float gg = acc[m][2][r] + bg;
      float go = acc[m][3][r] + bo;
      float cprev = c0[(size_t)row * TH + hc];
      float ig = 1.0f / (1.0f + __expf(-gi));
      float fg = 1.0f / (1.0f + __expf(-gf));
      float og = 1.0f / (1.0f + __expf(-go));
      float cn = fg * cprev + ig * tanhf(gg);
      float hn = og * tanhf(cn);
      h_out[(size_t)row * TH + hc] = hn;
      c_out[(size_t)row * TH + hc] = cn;
    }
  }
}

extern "C" void kernel_launch(void* const* d_in, const int* in_sizes, int n_in,
                              void* d_out, int out_size, void* d_ws, size_t ws_size,
                              hipStream_t stream) {
  const float* x    = (const float*)d_in[0];
  const float* h0   = (const float*)d_in[1];
  const float* c0   = (const float*)d_in[2];
  const float* w_ih = (const float*)d_in[3];
  const float* w_hh = (const float*)d_in[4];
  const float* b_ih = (const float*)d_in[5];
  const float* b_hh = (const float*)d_in[6];

  float* h_out = (float*)d_out;
  float* c_out = h_out + (size_t)TB * TH;

  f16* Uh = (f16*)d_ws;
  f16* Wh = Uh + (size_t)TB * TK;

  const int convBlocks = (2 * TB * TK / 4) / 256;  // 16384
  k_convert<<<convBlocks, 256, 0, stream>>>(x, h0, w_ih, w_hh, Uh, Wh);

  (void)hipFuncSetAttribute((const void*)k_lstm,
                            hipFuncAttributeMaxDynamicSharedMemorySize, 131072);
  k_lstm<<<256, 512, 131072, stream>>>(Uh, Wh, b_ih, b_hh, c0, h_out, c_out);
}